// Round 18
// baseline (68.074 us; speedup 1.0000x reference)
//
#include <hip/hip_runtime.h>

// Problem constants
#define B_    8
#define H_    512
#define W_    512
#define KK_   9
#define COUT_ 3
#define HO_   510
#define WO_   510
#define PLANE_ 260100           // HO_*WO_

__device__ __forceinline__ int iclamp(int v, int lo, int hi) {
    return v < lo ? lo : (v > hi ? hi : v);
}

typedef float f2a __attribute__((ext_vector_type(2), aligned(4)));

// R18 = R16 (best known: 4x16 wave patch, 1 px/thread, fused corner-pair
// gathers) + forced hoist of all 27 offset/mask stream loads.
// The asm keep-alive blocks the compiler's load-sinking (R15/R10 failure mode:
// VGPR stayed 24, loads re-serialized per tap). With all streams resident,
// every tap's gathers are immediately issuable -> latency overlaps.
__global__ __launch_bounds__(512, 4) void dcn_fwd_kernel(
    const float* __restrict__ x,       // [B,1,512,512]
    const float* __restrict__ offset,  // [B,18,510,510]
    const float* __restrict__ mask,    // [B,9,510,510]
    const float* __restrict__ weight,  // [3,1,3,3]
    const float* __restrict__ bias,    // [3]
    float* __restrict__ out)           // [B,3,510,510]
{
    const int bid  = blockIdx.x;       // 4 colblk * 128 band * 8 batch = 4096
    const int wt   = bid & 3;          // col-block (128 cols)
    const int band = (bid >> 2) & 127; // row band (4 rows)
    const int b    = bid >> 9;         // batch

    const int tid  = threadIdx.x;
    const int wave = tid >> 6;         // 0..7
    const int lane = tid & 63;
    const int r    = lane >> 4;        // 0..3
    const int c    = lane & 15;        // 0..15

    const int ho = band * 4 + r;
    const int wo = wt * 128 + wave * 16 + c;
    const bool valid = (ho < HO_) & (wo < WO_);
    const int ho_c = ho < HO_ ? ho : HO_ - 1;
    const int wo_c = wo < WO_ ? wo : WO_ - 1;

    const int pix = ho_c * WO_ + wo_c;
    const float* xb   = x + (b << 18);
    const float* offb = offset + b * (2 * KK_ * PLANE_) + pix;
    const float* mb   = mask   + b * (KK_ * PLANE_)    + pix;

    // ---- phase 1: issue ALL 27 stream loads; keep-alive defeats sinking ----
    float sdy[KK_], sdx[KK_], sm[KK_];
    #pragma unroll
    for (int kk = 0; kk < KK_; ++kk) {
        sdy[kk] = offb[(2 * kk)     * PLANE_];
        sdx[kk] = offb[(2 * kk + 1) * PLANE_];
        sm[kk]  = mb  [ kk          * PLANE_];
    }
    asm volatile("" ::
        "v"(sdy[0]), "v"(sdy[1]), "v"(sdy[2]), "v"(sdy[3]), "v"(sdy[4]),
        "v"(sdy[5]), "v"(sdy[6]), "v"(sdy[7]), "v"(sdy[8]),
        "v"(sdx[0]), "v"(sdx[1]), "v"(sdx[2]), "v"(sdx[3]), "v"(sdx[4]),
        "v"(sdx[5]), "v"(sdx[6]), "v"(sdx[7]), "v"(sdx[8]),
        "v"(sm[0]),  "v"(sm[1]),  "v"(sm[2]),  "v"(sm[3]),  "v"(sm[4]),
        "v"(sm[5]),  "v"(sm[6]),  "v"(sm[7]),  "v"(sm[8]));

    // weights/bias: uniform addresses -> scalar broadcast loads
    float w0[KK_], w1[KK_], w2[KK_];
    #pragma unroll
    for (int k = 0; k < KK_; ++k) {
        w0[k] = weight[0 * KK_ + k];
        w1[k] = weight[1 * KK_ + k];
        w2[k] = weight[2 * KK_ + k];
    }
    const float b0 = bias[0], b1 = bias[1], b2 = bias[2];

    const float fho = (float)ho_c;
    const float fwo = (float)wo_c;

    float acc0 = 0.f, acc1 = 0.f, acc2 = 0.f;

    // ---- phase 2: taps (all independent; gathers can all issue early) ----
    #pragma unroll
    for (int kh = 0; kh < 3; ++kh) {
        #pragma unroll
        for (int kw = 0; kw < 3; ++kw) {
            const int kk = kh * 3 + kw;
            const float py = (fho + (float)kh) + sdy[kk];
            const float px = (fwo + (float)kw) + sdx[kk];

            const float y0f = floorf(py);
            const float x0f = floorf(px);
            const float ly  = py - y0f;
            const float lx  = px - x0f;
            const float y1f = y0f + 1.0f;
            const float x1f = x0f + 1.0f;

            // validity on UNCLIPPED float corner coords (reference semantics)
            const float vy0 = (y0f >= 0.f && y0f <= 511.f) ? 1.f : 0.f;
            const float vy1 = (y1f >= 0.f && y1f <= 511.f) ? 1.f : 0.f;
            const float vx0 = (x0f >= 0.f && x0f <= 511.f) ? 1.f : 0.f;
            const float vx1 = (x1f >= 0.f && x1f <= 511.f) ? 1.f : 0.f;

            const int iy0 = (int)y0f;
            const int ix0 = (int)x0f;
            const int yi0 = iclamp(iy0,     0, 511);
            const int yi1 = iclamp(iy0 + 1, 0, 511);
            const int xc0 = iclamp(ix0,     0, 510);  // pair {xc0,xc0+1} in-bounds

            // one 8B load per row covers both horizontal corners (R16)
            const f2a q0 = *(const f2a*)(xb + (yi0 << 9) + xc0);
            const f2a q1 = *(const f2a*)(xb + (yi1 << 9) + xc0);

            const bool hi = (x0f >= 511.f);
            const bool lo = (x0f < 0.f);

            const float v00 = (hi ? q0.y : q0.x) * (vy0 * vx0);
            const float v01 = (lo ? q0.x : q0.y) * (vy0 * vx1);
            const float v10 = (hi ? q1.y : q1.x) * (vy1 * vx0);
            const float v11 = (lo ? q1.x : q1.y) * (vy1 * vx1);

            const float top = fmaf(lx, v01 - v00, v00);
            const float bot = fmaf(lx, v11 - v10, v10);
            const float val = fmaf(ly, bot - top, top);
            const float s   = val * sm[kk];
            acc0 = fmaf(w0[kk], s, acc0);
            acc1 = fmaf(w1[kk], s, acc1);
            acc2 = fmaf(w2[kk], s, acc2);
        }
    }

    if (valid) {
        const int ob = b * (COUT_ * PLANE_) + pix;
        out[ob]              = acc0 + b0;
        out[ob + PLANE_]     = acc1 + b1;
        out[ob + 2 * PLANE_] = acc2 + b2;
    }
}

extern "C" void kernel_launch(void* const* d_in, const int* in_sizes, int n_in,
                              void* d_out, int out_size, void* d_ws, size_t ws_size,
                              hipStream_t stream) {
    const float* x      = (const float*)d_in[0];
    const float* offset = (const float*)d_in[1];
    const float* mask   = (const float*)d_in[2];
    const float* weight = (const float*)d_in[3];
    const float* bias   = (const float*)d_in[4];
    float* out = (float*)d_out;

    const int grid = 4 * 128 * B_;   // colblk x band x batch = 4096
    dcn_fwd_kernel<<<grid, 512, 0, stream>>>(x, offset, mask, weight, bias, out);
}

// Round 19
// 52.950 us; speedup vs baseline: 1.2856x; 1.2856x over previous
//
#include <hip/hip_runtime.h>

// Problem constants
#define B_    8
#define H_    512
#define W_    512
#define KK_   9
#define COUT_ 3
#define HO_   510
#define WO_   510
#define PLANE_ 260100           // HO_*WO_

__device__ __forceinline__ int iclamp(int v, int lo, int hi) {
    return v < lo ? lo : (v > hi ? hi : v);
}

typedef float f2  __attribute__((ext_vector_type(2)));
typedef float f2a __attribute__((ext_vector_type(2), aligned(4)));

// R19 = R16 body (fused corner-pair gathers) x 2 px/thread (f2 streams/stores)
//     + sched_barrier(0) between the two pixel bodies.
// R17 showed 33 VMEM/px is reachable but the compiler pipelines both pixels'
// gather state -> VGPR 64 -> occupancy 39%. The barrier forbids hoisting
// pixel 1's gathers into pixel 0's live range: instruction count stays 33/px,
// peak register state is one pixel's worth (~R16 + f2 streams).
__global__ __launch_bounds__(512, 4) void dcn_fwd_kernel(
    const float* __restrict__ x,       // [B,1,512,512]
    const float* __restrict__ offset,  // [B,18,510,510]
    const float* __restrict__ mask,    // [B,9,510,510]
    const float* __restrict__ weight,  // [3,1,3,3]
    const float* __restrict__ bias,    // [3]
    float* __restrict__ out)           // [B,3,510,510]
{
    const int bid  = blockIdx.x;       // 2 colblk * 128 band * 8 batch = 2048
    const int wt   = bid & 1;          // col-block (256 cols)
    const int band = (bid >> 1) & 127; // row band (4 rows)
    const int b    = bid >> 8;         // batch

    const int tid  = threadIdx.x;
    const int wave = tid >> 6;         // 0..7
    const int lane = tid & 63;
    const int r    = lane >> 4;        // 0..3
    const int c    = lane & 15;        // 0..15

    int ho = band * 4 + r;             // 0..511
    const bool vrow = (ho < HO_);
    if (!vrow) ho = HO_ - 1;           // clamp for safe loads; stores predicated
    int wo0 = wt * 256 + wave * 32 + 2 * c;   // 0..510, even
    if (wo0 > WO_ - 2) wo0 = WO_ - 2;  // duplicate last pair (benign)

    const int pix = ho * WO_ + wo0;    // even -> f2 streams 8B aligned
    const float* xb   = x + (b << 18);
    const float* offb = offset + b * (2 * KK_ * PLANE_) + pix;
    const float* mb   = mask   + b * (KK_ * PLANE_)    + pix;

    // weights/bias: uniform addresses -> scalar broadcast loads
    float w0[KK_], w1[KK_], w2[KK_];
    #pragma unroll
    for (int k = 0; k < KK_; ++k) {
        w0[k] = weight[0 * KK_ + k];
        w1[k] = weight[1 * KK_ + k];
        w2[k] = weight[2 * KK_ + k];
    }
    const float b0 = bias[0], b1 = bias[1], b2 = bias[2];

    const float fho = (float)ho;
    const float fwo = (float)wo0;

    float a00 = 0.f, a01 = 0.f;   // cout0 px{0,1}
    float a10 = 0.f, a11 = 0.f;
    float a20 = 0.f, a21 = 0.f;

    #pragma unroll
    for (int kh = 0; kh < 3; ++kh) {
        #pragma unroll
        for (int kw = 0; kw < 3; ++kw) {
            const int kk = kh * 3 + kw;
            const f2 dy2 = *(const f2*)(offb + (2 * kk)     * PLANE_);
            const f2 dx2 = *(const f2*)(offb + (2 * kk + 1) * PLANE_);
            const f2 m2  = *(const f2*)(mb   +  kk          * PLANE_);

            #pragma unroll
            for (int p = 0; p < 2; ++p) {
                const float py = (fho + (float)kh) + dy2[p];
                const float px = (fwo + (float)(kw + p)) + dx2[p];

                const float y0f = floorf(py);
                const float x0f = floorf(px);
                const float ly  = py - y0f;
                const float lx  = px - x0f;
                const float y1f = y0f + 1.0f;
                const float x1f = x0f + 1.0f;

                // validity on UNCLIPPED float corner coords (reference semantics)
                const float vy0 = (y0f >= 0.f && y0f <= 511.f) ? 1.f : 0.f;
                const float vy1 = (y1f >= 0.f && y1f <= 511.f) ? 1.f : 0.f;
                const float vx0 = (x0f >= 0.f && x0f <= 511.f) ? 1.f : 0.f;
                const float vx1 = (x1f >= 0.f && x1f <= 511.f) ? 1.f : 0.f;

                const int iy0 = (int)y0f;
                const int ix0 = (int)x0f;
                const int yi0 = iclamp(iy0,     0, 511);
                const int yi1 = iclamp(iy0 + 1, 0, 511);
                const int xc0 = iclamp(ix0,     0, 510);  // pair {xc0,xc0+1} in-bounds

                // one 8B load per row covers both horizontal corners (R16)
                const f2a q0 = *(const f2a*)(xb + (yi0 << 9) + xc0);
                const f2a q1 = *(const f2a*)(xb + (yi1 << 9) + xc0);

                const bool hi = (x0f >= 511.f);
                const bool lo = (x0f < 0.f);

                const float v00 = (hi ? q0.y : q0.x) * (vy0 * vx0);
                const float v01 = (lo ? q0.x : q0.y) * (vy0 * vx1);
                const float v10 = (hi ? q1.y : q1.x) * (vy1 * vx0);
                const float v11 = (lo ? q1.x : q1.y) * (vy1 * vx1);

                const float top = fmaf(lx, v01 - v00, v00);
                const float bot = fmaf(lx, v11 - v10, v10);
                const float val = fmaf(ly, bot - top, top);
                const float s   = val * m2[p];

                if (p == 0) {
                    a00 = fmaf(w0[kk], s, a00);
                    a10 = fmaf(w1[kk], s, a10);
                    a20 = fmaf(w2[kk], s, a20);
                    // wall between pixel 0 and pixel 1: forbids pipelining both
                    // pixels' gather state (R17's VGPR-64 failure mode)
                    __builtin_amdgcn_sched_barrier(0);
                } else {
                    a01 = fmaf(w0[kk], s, a01);
                    a11 = fmaf(w1[kk], s, a11);
                    a21 = fmaf(w2[kk], s, a21);
                }
            }
        }
    }

    if (vrow) {
        const int ob = b * (COUT_ * PLANE_) + pix;
        f2 o0 = {a00 + b0, a01 + b0};
        f2 o1 = {a10 + b1, a11 + b1};
        f2 o2 = {a20 + b2, a21 + b2};
        *(f2*)(out + ob)              = o0;
        *(f2*)(out + ob + PLANE_)     = o1;
        *(f2*)(out + ob + 2 * PLANE_) = o2;
    }
}

extern "C" void kernel_launch(void* const* d_in, const int* in_sizes, int n_in,
                              void* d_out, int out_size, void* d_ws, size_t ws_size,
                              hipStream_t stream) {
    const float* x      = (const float*)d_in[0];
    const float* offset = (const float*)d_in[1];
    const float* mask   = (const float*)d_in[2];
    const float* weight = (const float*)d_in[3];
    const float* bias   = (const float*)d_in[4];
    float* out = (float*)d_out;

    const int grid = 2 * 128 * B_;   // colblk x band x batch = 2048
    dcn_fwd_kernel<<<grid, 512, 0, stream>>>(x, offset, mask, weight, bias, out);
}